// Round 14
// baseline (11004.810 us; speedup 1.0000x reference)
//
#include <hip/hip_runtime.h>
#include <cstdio>

// R14: dtype fix. R13's device-byte probes proved ALL float tensors are FP32
// (not bf16 — the error label's "bf16" is generator boilerplate) and edges are
// int32 pairs. Rounds 1-13 ran fine but parsed fp32 bits as bf16 -> NaN -> a
// tiny constant output whose absmax error equals max|ref| = 0.4492188,
// indistinguishable from "nothing ran". This round: pure fp32 pipeline,
// no diagnostics in kernel_launch (graph-capture safe).

__attribute__((constructor)) static void atomgnn_r14_load_beacon() {
    fprintf(stderr, "ATOMGNN_R14_SOURCE_LOADED\n");
    fflush(stderr);
}

#define NN_REF 100000
#define NE_REF 3200000

// zero a float buffer, grid-stride
__global__ void __launch_bounds__(256)
k_zero(float* __restrict__ p, int n)
{
    int i = blockIdx.x * 256 + threadIdx.x;
    int stride = gridDim.x * 256;
    for (; i < n; i += stride) p[i] = 0.0f;
}

// encoder: h = relu(nf @ w1 + b1) @ w2 + b2   (16 -> 32 -> 32)
__global__ void __launch_bounds__(256)
k_encode(const float* __restrict__ nf,
         const float* __restrict__ w1g, const float* __restrict__ b1g,
         const float* __restrict__ w2g, const float* __restrict__ b2g,
         float* __restrict__ h, int n_nodes)
{
    __shared__ float sw1[16 * 32];
    __shared__ float sw2[32 * 32];
    __shared__ float sb1[32];
    __shared__ float sb2[32];
    for (int i = threadIdx.x; i < 16 * 32; i += 256) sw1[i] = w1g[i];
    for (int i = threadIdx.x; i < 32 * 32; i += 256) sw2[i] = w2g[i];
    if (threadIdx.x < 32) {
        sb1[threadIdx.x] = b1g[threadIdx.x];
        sb2[threadIdx.x] = b2g[threadIdx.x];
    }
    __syncthreads();
    int n = blockIdx.x * 256 + threadIdx.x;
    if (n >= n_nodes) return;

    const float4* p = (const float4*)(nf + (size_t)n * 16);
    float x[16];
    #pragma unroll
    for (int c = 0; c < 4; c++) {
        float4 v = p[c];
        x[4 * c] = v.x; x[4 * c + 1] = v.y; x[4 * c + 2] = v.z; x[4 * c + 3] = v.w;
    }

    float acc[32];
    #pragma unroll
    for (int j = 0; j < 32; j++) acc[j] = sb1[j];
    #pragma unroll 4
    for (int k = 0; k < 16; k++) {
        float xk = x[k];
        const float* wr = &sw1[k * 32];
        #pragma unroll
        for (int j = 0; j < 32; j++) acc[j] = fmaf(xk, wr[j], acc[j]);
    }
    #pragma unroll
    for (int j = 0; j < 32; j++) acc[j] = fmaxf(acc[j], 0.0f);

    float o[32];
    #pragma unroll
    for (int j = 0; j < 32; j++) o[j] = sb2[j];
    #pragma unroll 4
    for (int k = 0; k < 32; k++) {
        float hk = acc[k];
        const float* wr = &sw2[k * 32];
        #pragma unroll
        for (int j = 0; j < 32; j++) o[j] = fmaf(hk, wr[j], o[j]);
    }
    float4* hp = (float4*)(h + (size_t)n * 32);
    #pragma unroll
    for (int c = 0; c < 8; c++)
        hp[c] = make_float4(o[4 * c], o[4 * c + 1], o[4 * c + 2], o[4 * c + 3]);
}

// message: m = relu([h[src],h[dst],ef] @ w1 + b1) @ w2 + b2; agg[dst] += m
__global__ void __launch_bounds__(256)
k_message(const float* __restrict__ h, const int2* __restrict__ edges,
          const float4* __restrict__ ef,
          const float* __restrict__ w1g, const float* __restrict__ b1g,
          const float* __restrict__ w2g, const float* __restrict__ b2g,
          float* __restrict__ agg, int n_edges)
{
    __shared__ float sw1[68 * 32];
    __shared__ float sw2[32 * 32];
    __shared__ float sb1[32];
    __shared__ float sb2[32];
    for (int i = threadIdx.x; i < 68 * 32; i += 256) sw1[i] = w1g[i];
    for (int i = threadIdx.x; i < 32 * 32; i += 256) sw2[i] = w2g[i];
    if (threadIdx.x < 32) {
        sb1[threadIdx.x] = b1g[threadIdx.x];
        sb2[threadIdx.x] = b2g[threadIdx.x];
    }
    __syncthreads();
    int e = blockIdx.x * 256 + threadIdx.x;
    if (e >= n_edges) return;

    int2 ed = edges[e];
    const float4* hs = (const float4*)(h + (size_t)ed.x * 32);
    const float4* hd = (const float4*)(h + (size_t)ed.y * 32);

    float acc[32];
    #pragma unroll
    for (int j = 0; j < 32; j++) acc[j] = sb1[j];

    #pragma unroll 2
    for (int c = 0; c < 8; c++) {
        float4 xv = hs[c];
        float xs[4] = {xv.x, xv.y, xv.z, xv.w};
        #pragma unroll
        for (int kk = 0; kk < 4; kk++) {
            float xk = xs[kk];
            const float* wr = &sw1[(c * 4 + kk) * 32];
            #pragma unroll
            for (int j = 0; j < 32; j++) acc[j] = fmaf(xk, wr[j], acc[j]);
        }
    }
    #pragma unroll 2
    for (int c = 0; c < 8; c++) {
        float4 xv = hd[c];
        float xs[4] = {xv.x, xv.y, xv.z, xv.w};
        #pragma unroll
        for (int kk = 0; kk < 4; kk++) {
            float xk = xs[kk];
            const float* wr = &sw1[(32 + c * 4 + kk) * 32];
            #pragma unroll
            for (int j = 0; j < 32; j++) acc[j] = fmaf(xk, wr[j], acc[j]);
        }
    }
    {
        float4 ev = ef[e];
        float ex[4] = {ev.x, ev.y, ev.z, ev.w};
        #pragma unroll
        for (int kk = 0; kk < 4; kk++) {
            float xk = ex[kk];
            const float* wr = &sw1[(64 + kk) * 32];
            #pragma unroll
            for (int j = 0; j < 32; j++) acc[j] = fmaf(xk, wr[j], acc[j]);
        }
    }
    #pragma unroll
    for (int j = 0; j < 32; j++) acc[j] = fmaxf(acc[j], 0.0f);

    float o[32];
    #pragma unroll
    for (int j = 0; j < 32; j++) o[j] = sb2[j];
    #pragma unroll 4
    for (int k = 0; k < 32; k++) {
        float hk = acc[k];
        const float* wr = &sw2[k * 32];
        #pragma unroll
        for (int j = 0; j < 32; j++) o[j] = fmaf(hk, wr[j], o[j]);
    }

    float* ap = agg + (size_t)ed.y * 32;
    #pragma unroll
    for (int j = 0; j < 32; j++) atomicAdd(ap + j, o[j]);
}

// update: h = h + relu([h,agg] @ w1 + b1) @ w2 + b2, in place per row
__global__ void __launch_bounds__(256)
k_update(float* h, const float* __restrict__ agg,
         const float* __restrict__ w1g, const float* __restrict__ b1g,
         const float* __restrict__ w2g, const float* __restrict__ b2g,
         int n_nodes)
{
    __shared__ float sw1[64 * 32];
    __shared__ float sw2[32 * 32];
    __shared__ float sb1[32];
    __shared__ float sb2[32];
    for (int i = threadIdx.x; i < 64 * 32; i += 256) sw1[i] = w1g[i];
    for (int i = threadIdx.x; i < 32 * 32; i += 256) sw2[i] = w2g[i];
    if (threadIdx.x < 32) {
        sb1[threadIdx.x] = b1g[threadIdx.x];
        sb2[threadIdx.x] = b2g[threadIdx.x];
    }
    __syncthreads();
    int n = blockIdx.x * 256 + threadIdx.x;
    if (n >= n_nodes) return;

    const float4* hp = (const float4*)(h + (size_t)n * 32);
    const float4* ap = (const float4*)(agg + (size_t)n * 32);

    float hv[32];
    float acc[32];
    #pragma unroll
    for (int j = 0; j < 32; j++) acc[j] = sb1[j];

    #pragma unroll 2
    for (int c = 0; c < 8; c++) {
        float4 xv = hp[c];
        hv[4 * c] = xv.x; hv[4 * c + 1] = xv.y; hv[4 * c + 2] = xv.z; hv[4 * c + 3] = xv.w;
        float xs[4] = {xv.x, xv.y, xv.z, xv.w};
        #pragma unroll
        for (int kk = 0; kk < 4; kk++) {
            float xk = xs[kk];
            const float* wr = &sw1[(c * 4 + kk) * 32];
            #pragma unroll
            for (int j = 0; j < 32; j++) acc[j] = fmaf(xk, wr[j], acc[j]);
        }
    }
    #pragma unroll 2
    for (int c = 0; c < 8; c++) {
        float4 xv = ap[c];
        float xs[4] = {xv.x, xv.y, xv.z, xv.w};
        #pragma unroll
        for (int kk = 0; kk < 4; kk++) {
            float xk = xs[kk];
            const float* wr = &sw1[(32 + c * 4 + kk) * 32];
            #pragma unroll
            for (int j = 0; j < 32; j++) acc[j] = fmaf(xk, wr[j], acc[j]);
        }
    }
    #pragma unroll
    for (int j = 0; j < 32; j++) acc[j] = fmaxf(acc[j], 0.0f);

    float o[32];
    #pragma unroll
    for (int j = 0; j < 32; j++) o[j] = sb2[j];
    #pragma unroll 4
    for (int k = 0; k < 32; k++) {
        float hk = acc[k];
        const float* wr = &sw2[k * 32];
        #pragma unroll
        for (int j = 0; j < 32; j++) o[j] = fmaf(hk, wr[j], o[j]);
    }

    float4* op = (float4*)(h + (size_t)n * 32);
    #pragma unroll
    for (int c = 0; c < 8; c++)
        op[c] = make_float4(hv[4 * c] + o[4 * c], hv[4 * c + 1] + o[4 * c + 1],
                            hv[4 * c + 2] + o[4 * c + 2], hv[4 * c + 3] + o[4 * c + 3]);
}

// head: out = (relu(h @ w1 + b1) @ w2 + b2)[:, 0]   (fp32 out)
__global__ void AtomGNN_56169582297457_kernel(const float* h, const float* w1g, const float* b1g, const float* w2g, const float* b2g, float* out, int n_nodes) {
    __shared__ float sw1[32 * 32];
    __shared__ float sb1[32];
    __shared__ float sw2[32];
    __shared__ float sb2;
    for (int i = threadIdx.x; i < 32 * 32; i += 256) sw1[i] = w1g[i];
    if (threadIdx.x < 32) {
        sb1[threadIdx.x] = b1g[threadIdx.x];
        sw2[threadIdx.x] = w2g[threadIdx.x];
    }
    if (threadIdx.x == 0) sb2 = b2g[0];
    __syncthreads();
    int n = blockIdx.x * 256 + threadIdx.x;
    if (n >= n_nodes) return;

    const float4* hp = (const float4*)(h + (size_t)n * 32);
    float x[32];
    #pragma unroll
    for (int c = 0; c < 8; c++) {
        float4 xv = hp[c];
        x[4 * c] = xv.x; x[4 * c + 1] = xv.y; x[4 * c + 2] = xv.z; x[4 * c + 3] = xv.w;
    }
    float acc[32];
    #pragma unroll
    for (int j = 0; j < 32; j++) acc[j] = sb1[j];
    #pragma unroll 4
    for (int k = 0; k < 32; k++) {
        float xk = x[k];
        const float* wr = &sw1[k * 32];
        #pragma unroll
        for (int j = 0; j < 32; j++) acc[j] = fmaf(xk, wr[j], acc[j]);
    }
    float val = sb2;
    #pragma unroll
    for (int k = 0; k < 32; k++) val = fmaf(fmaxf(acc[k], 0.0f), sw2[k], val);
    out[n] = val;
}

extern "C" void kernel_launch(void* const* d_in, const int* in_sizes, int n_in,
                              void* d_out, int out_size, void* d_ws, size_t ws_size,
                              hipStream_t stream) {
    const float* nf      = (const float*)d_in[0];
    const int2*  edges   = (const int2*)d_in[1];
    const float4* ef     = (const float4*)d_in[2];
    const float* enc_w1  = (const float*)d_in[3];
    const float* enc_b1  = (const float*)d_in[4];
    const float* enc_w2  = (const float*)d_in[5];
    const float* enc_b2  = (const float*)d_in[6];
    const float* msg_w1  = (const float*)d_in[7];
    const float* msg_b1  = (const float*)d_in[8];
    const float* msg_w2  = (const float*)d_in[9];
    const float* msg_b2  = (const float*)d_in[10];
    const float* upd_w1  = (const float*)d_in[11];
    const float* upd_b1  = (const float*)d_in[12];
    const float* upd_w2  = (const float*)d_in[13];
    const float* upd_b2  = (const float*)d_in[14];
    const float* head_w1 = (const float*)d_in[15];
    const float* head_b1 = (const float*)d_in[16];
    const float* head_w2 = (const float*)d_in[17];
    const float* head_b2 = (const float*)d_in[18];

    int n_nodes = (out_size > 0) ? out_size : NN_REF;
    int n_edges = (in_sizes && n_in > 2 && in_sizes[2] > 0) ? in_sizes[2] / 4 : NE_REF;

    float* h   = (float*)d_ws;                    // [n_nodes, 32] f32
    float* agg = h + (size_t)n_nodes * 32;        // [n_nodes, 32] f32

    int nb_nodes = (n_nodes + 255) / 256;
    int nb_edges = (n_edges + 255) / 256;

    k_encode<<<nb_nodes, 256, 0, stream>>>(nf, enc_w1, enc_b1, enc_w2, enc_b2, h, n_nodes);

    for (int r = 0; r < 2; r++) {
        k_zero<<<1024, 256, 0, stream>>>(agg, n_nodes * 32);
        k_message<<<nb_edges, 256, 0, stream>>>(
            h, edges, ef,
            msg_w1 + (size_t)r * 68 * 32, msg_b1 + (size_t)r * 32,
            msg_w2 + (size_t)r * 32 * 32, msg_b2 + (size_t)r * 32,
            agg, n_edges);
        k_update<<<nb_nodes, 256, 0, stream>>>(
            h, agg,
            upd_w1 + (size_t)r * 64 * 32, upd_b1 + (size_t)r * 32,
            upd_w2 + (size_t)r * 32 * 32, upd_b2 + (size_t)r * 32,
            n_nodes);
    }

    AtomGNN_56169582297457_kernel<<<nb_nodes, 256, 0, stream>>>(
        h, head_w1, head_b1, head_w2, head_b2, (float*)d_out, n_nodes);
}